// Round 1
// baseline (1715.102 us; speedup 1.0000x reference)
//
#include <hip/hip_runtime.h>
#include <hip/hip_fp16.h>

// MOF_Net: two edge-MLP passes (shared Linear(128,128)+ReLU+Linear(128,64)) + segment sums.
// Stage A: msg2 = MLP(concat(x2[src2], ea2)) -> pk_f16 atomicAdd into e1acc[dst2]   (E2 rows)
// Stage B: msg1 = MLP(concat(x1[src1], ea1 + e1acc)) -> pk_f16 atomicAdd into h[dst1] (E1 rows)
// Stage C: pool h by sorted batch -> out[256][64], /2.

typedef __attribute__((ext_vector_type(8))) short short8;   // 8 x bf16 (guide §3)
typedef __attribute__((ext_vector_type(4))) float f32x4;

#define NE1 800000
#define NE2 1600000
#define NN1 50000
#define NG  256

__device__ __forceinline__ unsigned short f2bf(float f) {
  unsigned u = __float_as_uint(f);
  u += 0x7fffu + ((u >> 16) & 1u);          // RTNE
  return (unsigned short)(u >> 16);
}

__device__ __forceinline__ short8 cvt8(f32x4 a, f32x4 b) {
  short8 s;
  s[0] = (short)f2bf(a[0]); s[1] = (short)f2bf(a[1]);
  s[2] = (short)f2bf(a[2]); s[3] = (short)f2bf(a[3]);
  s[4] = (short)f2bf(b[0]); s[5] = (short)f2bf(b[1]);
  s[6] = (short)f2bf(b[2]); s[7] = (short)f2bf(b[3]);
  return s;
}

// Pre-transpose + bf16-convert + XOR-swizzle weights into ws images.
// image byte offset for WT[n][k]: n*256 + ((2k) ^ ((n&7)<<4))  -- 16B-chunk swizzle
__global__ void prep_weights(const float* __restrict__ W1, const float* __restrict__ W2,
                             unsigned short* __restrict__ W1img, unsigned short* __restrict__ W2img) {
  int t = blockIdx.x * blockDim.x + threadIdx.x;
  int stride = gridDim.x * blockDim.x;
  for (int e = t; e < 128*128 + 128*64; e += stride) {
    if (e < 16384) {                       // W1 [128k][128n]
      int k = e >> 7, n = e & 127;
      unsigned off = n * 256u + ((2u * (unsigned)k) ^ ((unsigned)(n & 7) << 4));
      W1img[off >> 1] = f2bf(W1[k * 128 + n]);
    } else {                               // W2 [128k][64d]
      int e2 = e - 16384;
      int k = e2 >> 6, d = e2 & 63;
      unsigned off = d * 256u + ((2u * (unsigned)k) ^ ((unsigned)(d & 7) << 4));
      W2img[off >> 1] = f2bf(W2[k * 64 + d]);
    }
  }
}

// Block = 256 threads = 4 waves; each wave owns 32 edge rows (2 r-tiles of 16).
// Swapped MFMA: D = A(Wt) * B(featT): B-frag = 8 contiguous feats of one row -> direct global gather.
// LDS: W1t swz 32KB | W2t swz 16KB | 4 x 4KB per-wave H ping-pong = 64KB -> 2 blocks/CU.
template<bool HASB2>
__global__ __launch_bounds__(256, 2) void mlp_stage(
    const float* __restrict__ featA, const int* __restrict__ idxA,
    const float* __restrict__ featB, const __half2* __restrict__ featB2,
    const int* __restrict__ idxOut, __half2* __restrict__ outAcc,
    const float* __restrict__ b1, const float* __restrict__ b2,
    const unsigned short* __restrict__ W1img, const unsigned short* __restrict__ W2img,
    int nTiles) {
  __shared__ unsigned short lds16[32768];   // 64 KB
  const int tid  = threadIdx.x;
  const int lane = tid & 63;
  const int wave = tid >> 6;
  const int g = lane >> 4;                  // 0..3  (k-group)
  const int r = lane & 15;                  // 0..15

  { // stage swizzled weight images linearly into LDS (conflict-free b128)
    int4* ldsv = reinterpret_cast<int4*>(lds16);
    const int4* s1 = reinterpret_cast<const int4*>(W1img);
    const int4* s2 = reinterpret_cast<const int4*>(W2img);
#pragma unroll
    for (int i = 0; i < 8; ++i) ldsv[tid + 256 * i] = s1[tid + 256 * i];
#pragma unroll
    for (int i = 0; i < 4; ++i) ldsv[2048 + tid + 256 * i] = s2[tid + 256 * i];
  }
  __syncthreads();

  const char* W1l = (const char*)lds16;             // 32KB
  const char* W2l = (const char*)lds16 + 32768;     // 16KB
  char* Hb = (char*)lds16 + 49152 + wave * 4096;    // per-wave 4KB H buffer

  for (int tile = blockIdx.x; tile < nTiles; tile += gridDim.x) {
    const int rowBase = tile * 128 + wave * 32;

    // ---- load edge fragments: lane holds feats [8g+j] of row (rowBase+rt*16+r), per 32-col window ks
    short8 ef[2][4];
    int dstRow[2];
#pragma unroll
    for (int rt = 0; rt < 2; ++rt) {
      const int row = rowBase + rt * 16 + r;
      const int sa = idxA[row];
      const float* pA = featA + (long)sa * 64 + 8 * g;   // cols 0..63  = gathered table row
      const float* pB = featB + (long)row * 64 + 8 * g;  // cols 64..127 = per-edge attr
      f32x4 a0 = *(const f32x4*)(pA);
      f32x4 a1 = *(const f32x4*)(pA + 4);
      f32x4 a2 = *(const f32x4*)(pA + 32);
      f32x4 a3 = *(const f32x4*)(pA + 36);
      f32x4 c0 = *(const f32x4*)(pB);
      f32x4 c1 = *(const f32x4*)(pB + 4);
      f32x4 c2 = *(const f32x4*)(pB + 32);
      f32x4 c3 = *(const f32x4*)(pB + 36);
      if (HASB2) {  // stage B: += e1acc (f16 accumulated)
        const __half2* pC = featB2 + (long)row * 32 + 4 * g;
        float2 q0 = __half22float2(pC[0]), q1 = __half22float2(pC[1]);
        float2 q2 = __half22float2(pC[2]), q3 = __half22float2(pC[3]);
        c0[0] += q0.x; c0[1] += q0.y; c0[2] += q1.x; c0[3] += q1.y;
        c1[0] += q2.x; c1[1] += q2.y; c1[2] += q3.x; c1[3] += q3.y;
        float2 q4 = __half22float2(pC[16]), q5 = __half22float2(pC[17]);
        float2 q6 = __half22float2(pC[18]), q7 = __half22float2(pC[19]);
        c2[0] += q4.x; c2[1] += q4.y; c2[2] += q5.x; c2[3] += q5.y;
        c3[0] += q6.x; c3[1] += q6.y; c3[2] += q7.x; c3[3] += q7.y;
      }
      ef[rt][0] = cvt8(a0, a1);
      ef[rt][1] = cvt8(a2, a3);
      ef[rt][2] = cvt8(c0, c1);
      ef[rt][3] = cvt8(c2, c3);
      dstRow[rt] = idxOut[row];
    }

    // ---- matmul1: C1[n-tile t] = sum_ks W1T-frag(t,ks) x ef(ks);  D: row=n(4g+i), col=r
    f32x4 C1[2][8];
#pragma unroll
    for (int rt = 0; rt < 2; ++rt)
#pragma unroll
      for (int t = 0; t < 8; ++t) C1[rt][t] = (f32x4){0.f, 0.f, 0.f, 0.f};

#pragma unroll
    for (int ks = 0; ks < 4; ++ks) {
#pragma unroll
      for (int t = 0; t < 8; ++t) {
        const int n = 16 * t + r;
        const int off = n * 256 + ((ks * 64 + g * 16) ^ ((n & 7) << 4));
        short8 wf = *(const short8*)(W1l + off);
        C1[0][t] = __builtin_amdgcn_mfma_f32_16x16x32_bf16(wf, ef[0][ks], C1[0][t], 0, 0, 0);
        C1[1][t] = __builtin_amdgcn_mfma_f32_16x16x32_bf16(wf, ef[1][ks], C1[1][t], 0, 0, 0);
      }
    }

#pragma unroll
    for (int rt = 0; rt < 2; ++rt) {
      // bias + relu + pack -> H buffer, laid out so B2-frag read is linear b128:
      // value n of row r lands at byte (n>>5)*1024 + (((n>>3)&3)*16 + r)*16 + (n&7)*2
#pragma unroll
      for (int t = 0; t < 8; ++t) {
        f32x4 bq = *(const f32x4*)(b1 + 16 * t + 4 * g);
        float h0 = fmaxf(C1[rt][t][0] + bq[0], 0.f);
        float h1 = fmaxf(C1[rt][t][1] + bq[1], 0.f);
        float h2 = fmaxf(C1[rt][t][2] + bq[2], 0.f);
        float h3 = fmaxf(C1[rt][t][3] + bq[3], 0.f);
        unsigned lo = (unsigned)f2bf(h0) | ((unsigned)f2bf(h1) << 16);
        unsigned hi = (unsigned)f2bf(h2) | ((unsigned)f2bf(h3) << 16);
        const int woff = (t >> 1) * 1024 + (((2 * t + (g >> 1)) & 3) * 16 + r) * 16 + 8 * (g & 1);
        *(uint2*)(Hb + woff) = make_uint2(lo, hi);
      }
      // matmul2: D2: row=d(4g+i), col=r ; B-frag = h[r][32ks+8g+j] = linear read at lane*16
      f32x4 C2[4];
#pragma unroll
      for (int dt = 0; dt < 4; ++dt) C2[dt] = (f32x4){0.f, 0.f, 0.f, 0.f};
#pragma unroll
      for (int ks = 0; ks < 4; ++ks) {
        short8 hf = *(const short8*)(Hb + ks * 1024 + lane * 16);
#pragma unroll
        for (int dt = 0; dt < 4; ++dt) {
          const int d = 16 * dt + r;
          const int off2 = d * 256 + ((ks * 64 + g * 16) ^ ((d & 7) << 4));
          short8 w2f = *(const short8*)(W2l + off2);
          C2[dt] = __builtin_amdgcn_mfma_f32_16x16x32_bf16(w2f, hf, C2[dt], 0, 0, 0);
        }
      }
      // scatter: + b2, packed f16 atomic add (2 floats per op)
      __half2* outRow = outAcc + (long)dstRow[rt] * 32;
#pragma unroll
      for (int dt = 0; dt < 4; ++dt) {
        f32x4 b2q = *(const f32x4*)(b2 + 16 * dt + 4 * g);
        float v0 = C2[dt][0] + b2q[0];
        float v1 = C2[dt][1] + b2q[1];
        float v2 = C2[dt][2] + b2q[2];
        float v3 = C2[dt][3] + b2q[3];
        unsafeAtomicAdd(outRow + 8 * dt + 2 * g,     __floats2half2_rn(v0, v1));
        unsafeAtomicAdd(outRow + 8 * dt + 2 * g + 1, __floats2half2_rn(v2, v3));
      }
    }
  }
}

// batch is sorted: per-thread register accumulation, atomic only on graph transition.
__global__ void pool_kernel(const __half* __restrict__ h, const int* __restrict__ batch,
                            float* __restrict__ out, int N) {
  const int d = threadIdx.x & 63;
  const int sub = threadIdx.x >> 6;        // wave id: whole wave shares one row -> uniform branch
  const int rend = min((int)(blockIdx.x * 1024 + 1024), N);
  float acc = 0.f;
  int gcur = -1;
  for (int r2 = blockIdx.x * 1024 + sub; r2 < rend; r2 += 4) {
    int gb = batch[r2];
    float v = __half2float(h[(long)r2 * 64 + d]);
    if (gb != gcur) {
      if (gcur >= 0) atomicAdd(out + gcur * 64 + d, acc * 0.5f);
      gcur = gb; acc = v;
    } else {
      acc += v;
    }
  }
  if (gcur >= 0) atomicAdd(out + gcur * 64 + d, acc * 0.5f);
}

extern "C" void kernel_launch(void* const* d_in, const int* in_sizes, int n_in,
                              void* d_out, int out_size, void* d_ws, size_t ws_size,
                              hipStream_t stream) {
  const float* x1  = (const float*)d_in[0];
  const float* x2  = (const float*)d_in[1];
  const int* ei1   = (const int*)d_in[2];      // [2][E1]
  const int* ei2   = (const int*)d_in[3];      // [2][E2]
  const int* batch = (const int*)d_in[4];
  const float* ea1 = (const float*)d_in[5];
  const float* ea2 = (const float*)d_in[6];
  const float* W1  = (const float*)d_in[7];
  const float* b1  = (const float*)d_in[8];
  const float* W2  = (const float*)d_in[9];
  const float* b2  = (const float*)d_in[10];

  char* ws = (char*)d_ws;
  __half2* e1acc = (__half2*)ws;                               // 102,400,000 B
  __half2* hacc  = (__half2*)(ws + 102400000);                 //   6,400,000 B
  unsigned short* W1img = (unsigned short*)(ws + 108800000);   //      32,768 B
  unsigned short* W2img = (unsigned short*)(ws + 108832768);   //      16,384 B

  hipMemsetAsync(e1acc, 0, 102400000, stream);
  hipMemsetAsync(hacc, 0, 6400000, stream);
  hipMemsetAsync(d_out, 0, (size_t)NG * 64 * 4, stream);

  prep_weights<<<64, 256, 0, stream>>>(W1, W2, W1img, W2img);

  // Stage A: rows = E2 angles; gather x2[src2], attr ea2, scatter to e1acc[dst2]
  mlp_stage<false><<<512, 256, 0, stream>>>(x2, ei2, ea2, (const __half2*)nullptr,
                                            ei2 + NE2, e1acc, b1, b2, W1img, W2img, NE2 / 128);
  // Stage B: rows = E1 bonds; gather x1[src1], attr ea1 + e1acc, scatter to hacc[dst1]
  mlp_stage<true><<<512, 256, 0, stream>>>(x1, ei1, ea1, e1acc,
                                           ei1 + NE1, hacc, b1, b2, W1img, W2img, NE1 / 128);
  // Stage C: pool by sorted batch, /2
  pool_kernel<<<49, 256, 0, stream>>>((const __half*)hacc, batch, (float*)d_out, NN1);
}